// Round 15
// baseline (21.473 us; speedup 1.0000x reference)
//
#include <hip/hip_runtime.h>
#include <math.h>

// NUFFT forward via separable phase + bf16 MFMA. No workspace.
// ksp[c,k] = sum_x Ex[k,x] * ( sum_y img[c,x,y] * Ey[k,y] )
// R15: R14 template (LDS dbuf slab, 1 barrier/iter, proven swizzle +
// __sincosf) with wave = (2 coils x 4 k-quarters). Slab shrinks to 2 coils
// -> LDS 66 KB -> 2 blocks/CU -> 4 waves/SIMD (2x R14 TLP), same per-CU
// and total image traffic (128 MB L2). Per-lane staging halves, VGPR -40.
// Grid 512 = 4 coil-pairs x 128 k-groups (cg = bid>>7: adjacent blocks
// share coil images -> L2/L3 locality).

#define K_TOTAL 8192
#define KB      64          // k's per block (4 quarters of 16)
#define NX      128
#define NY      128
#define EY_LD   136         // bf16 row stride (pad +8)

typedef short  bf16x8 __attribute__((ext_vector_type(8)));
typedef float  f32x4  __attribute__((ext_vector_type(4)));

__device__ inline unsigned short f32_to_bf16_rne(float f) {
    unsigned int u = __float_as_uint(f);
    u += 0x7FFFu + ((u >> 16) & 1u);
    return (unsigned short)(u >> 16);
}
__device__ inline unsigned pack2(float a, float b) {
    return (unsigned)f32_to_bf16_rne(a) | ((unsigned)f32_to_bf16_rne(b) << 16);
}

__global__ __launch_bounds__(512, 2) void nufft_mfma_kernel(
    const float* __restrict__ imgR,
    const float* __restrict__ imgI,
    const float* __restrict__ trj,
    float* __restrict__ out)
{
    __shared__ __align__(16) unsigned short eyR[KB][EY_LD];
    __shared__ __align__(16) unsigned short eyI[KB][EY_LD];
    // double-buffered slabs: [buf][coil2][RI][16 rows * 128 y] bf16, swizzled
    __shared__ __align__(16) unsigned short slab[2][2][2][16 * 128];

    const int tid = threadIdx.x;
    const int bid = blockIdx.x;
    const int cg  = bid >> 7;          // coil pair: 0..3 -> coils 2cg,2cg+1
    const int kg0 = (bid & 127) * KB;  // base k of this block

    // ---- Phase A: Ey table, 64 rows (Ex on the fly in stage C) ----
    for (int i = tid; i < KB * 128; i += 512) {
        const int kk = i >> 7;
        const int p  = i & 127;
        const float ky = trj[(kg0 + kk) * 2 + 1];
        const float r  = (float)(p - 64) * (1.0f / 128.0f);
        float t = -ky * r; t -= floorf(t);           // revolutions in [0,1)
        float st, ct; __sincosf(6.283185307179586f * t, &st, &ct);
        eyR[kk][p] = f32_to_bf16_rne(ct);
        eyI[kk][p] = f32_to_bf16_rne(st);
    }
    __syncthreads();

    const int wave = tid >> 6;      // 0..7
    const int lane = tid & 63;
    const int l15  = lane & 15;
    const int lg   = lane >> 4;     // 0..3
    const int c2   = wave & 1;      // coil within pair (read side)
    const int kq   = wave >> 1;     // k-quarter: 16 k's
    const int c    = cg * 2 + c2;   // this wave's output coil
    const int srow = wave * 2 + (lane >> 5);  // staging row 0..15
    const int seg  = lane & 31;               // float4 segment in row

    // kx preload for stage C: k = kg0 + kq*16 + lg*4 + j
    float kxv[4];
#pragma unroll
    for (int j = 0; j < 4; ++j)
        kxv[j] = trj[(kg0 + kq * 16 + lg * 4 + j) * 2 + 0];

    // ---- A-fragment preload: Ey rows kq*16 + l15 (R4-proven layout) ----
    // A layout (16x16x32): row = lane&15, k slot = (lane>>4)*8 + idx.
    bf16x8 aR[4], aI[4];
#pragma unroll
    for (int ys = 0; ys < 4; ++ys) {
        const int row = kq * 16 + l15;
        const int y   = ys * 32 + lg * 8;
        aR[ys] = *(const bf16x8*)&eyR[row][y];
        aI[ys] = *(const bf16x8*)&eyI[row][y];
    }

    f32x4 outRe = {0,0,0,0};
    f32x4 outIm = {0,0,0,0};

    // staging: each thread owns (srow, seg) and stages all 4 {coil, RI}
    // combos there. 8 waves x 2 halves cover rows 0..15 exactly once.
    const int c0 = cg * 2;          // first coil of the pair
    float4 b0R, b0I, b1R, b1I;      // [coil0 R/I, coil1 R/I]

    // ---- prologue: tile 0 -> load, cvt, write slab[0] ----
    {
        const float* p0R = imgR + ((c0 + 0) * NX + srow) * NY + seg * 4;
        const float* p0I = imgI + ((c0 + 0) * NX + srow) * NY + seg * 4;
        const float* p1R = imgR + ((c0 + 1) * NX + srow) * NY + seg * 4;
        const float* p1I = imgI + ((c0 + 1) * NX + srow) * NY + seg * 4;
        b0R = *(const float4*)p0R; b0I = *(const float4*)p0I;
        b1R = *(const float4*)p1R; b1I = *(const float4*)p1I;

        const int off = srow * 256 + ((seg * 8) ^ ((srow & 15) << 4));
        uint2 v;
        v.x = pack2(b0R.x, b0R.y); v.y = pack2(b0R.z, b0R.w);
        *(uint2*)((char*)&slab[0][0][0][0] + off) = v;
        v.x = pack2(b0I.x, b0I.y); v.y = pack2(b0I.z, b0I.w);
        *(uint2*)((char*)&slab[0][0][1][0] + off) = v;
        v.x = pack2(b1R.x, b1R.y); v.y = pack2(b1R.z, b1R.w);
        *(uint2*)((char*)&slab[0][1][0][0] + off) = v;
        v.x = pack2(b1I.x, b1I.y); v.y = pack2(b1I.z, b1I.w);
        *(uint2*)((char*)&slab[0][1][1][0] + off) = v;
    }
    __syncthreads();

    // ---- main loop: 1 barrier/iter; prefetch overlaps MFMA+stageC ----
    for (int nt = 0; nt < 8; ++nt) {
        const int cur = nt & 1;
        const int x0  = nt * 16;

        // 1. prefetch tile nt+1 into regs (consumed in step 4)
        if (nt < 7) {
            const int xr = (nt + 1) * 16 + srow;
            b0R = *(const float4*)(imgR + ((c0 + 0) * NX + xr) * NY + seg * 4);
            b0I = *(const float4*)(imgI + ((c0 + 0) * NX + xr) * NY + seg * 4);
            b1R = *(const float4*)(imgR + ((c0 + 1) * NX + xr) * NY + seg * 4);
            b1I = *(const float4*)(imgI + ((c0 + 1) * NX + xr) * NY + seg * 4);
        }

        // 2. MFMA from slab[cur] (R7/R12/R14-proven swizzle/layout)
        const char* sbR = (const char*)&slab[cur][c2][0][0];
        const char* sbI = (const char*)&slab[cur][c2][1][0];
        f32x4 P = {0,0,0,0}, Q = {0,0,0,0}, U = {0,0,0,0}, V = {0,0,0,0};
        const int rowb = l15 * 256;
#pragma unroll
        for (int ys = 0; ys < 4; ++ys) {
            const int inb = (lg * 16 + ys * 64) ^ (l15 << 4);
            const bf16x8 bR = *(const bf16x8*)(sbR + rowb + inb);
            const bf16x8 bI = *(const bf16x8*)(sbI + rowb + inb);
            P = __builtin_amdgcn_mfma_f32_16x16x32_bf16(aR[ys], bR, P, 0, 0, 0);
            Q = __builtin_amdgcn_mfma_f32_16x16x32_bf16(aI[ys], bI, Q, 0, 0, 0);
            U = __builtin_amdgcn_mfma_f32_16x16x32_bf16(aR[ys], bI, U, 0, 0, 0);
            V = __builtin_amdgcn_mfma_f32_16x16x32_bf16(aI[ys], bR, V, 0, 0, 0);
        }

        // 3. stage C: Ex on the fly (proven __sincosf numerics)
        const float rx = (float)(x0 + l15 - 64) * (1.0f / 128.0f);
#pragma unroll
        for (int j = 0; j < 4; ++j) {
            float t = -kxv[j] * rx; t -= floorf(t);
            float eI_, eR_; __sincosf(6.283185307179586f * t, &eI_, &eR_);
            const float TR = P[j] - Q[j];
            const float TI = U[j] + V[j];
            outRe[j] += eR_ * TR - eI_ * TI;
            outIm[j] += eR_ * TI + eI_ * TR;
        }

        // 4. cvt + swizzled ds_write of tile nt+1 into slab[cur^1]
        if (nt < 7) {
            const int off = srow * 256 + ((seg * 8) ^ ((srow & 15) << 4));
            uint2 v;
            v.x = pack2(b0R.x, b0R.y); v.y = pack2(b0R.z, b0R.w);
            *(uint2*)((char*)&slab[cur ^ 1][0][0][0] + off) = v;
            v.x = pack2(b0I.x, b0I.y); v.y = pack2(b0I.z, b0I.w);
            *(uint2*)((char*)&slab[cur ^ 1][0][1][0] + off) = v;
            v.x = pack2(b1R.x, b1R.y); v.y = pack2(b1R.z, b1R.w);
            *(uint2*)((char*)&slab[cur ^ 1][1][0][0] + off) = v;
            v.x = pack2(b1I.x, b1I.y); v.y = pack2(b1I.z, b1I.w);
            *(uint2*)((char*)&slab[cur ^ 1][1][1][0] + off) = v;
        }

        __syncthreads();   // slab[cur^1] visible to all waves next iter
    }

    // ---- reduce over the 16 x-lanes; lanes with l15==0 write ----
#pragma unroll
    for (int j = 0; j < 4; ++j) {
        float r_ = outRe[j];
        float i_ = outIm[j];
#pragma unroll
        for (int m = 1; m < 16; m <<= 1) {
            r_ += __shfl_xor(r_, m, 64);
            i_ += __shfl_xor(i_, m, 64);
        }
        if (l15 == 0) {
            const int kg = kg0 + kq * 16 + lg * 4 + j;
            ((float2*)out)[c * K_TOTAL + kg] = make_float2(r_, i_);
        }
    }
}

extern "C" void kernel_launch(void* const* d_in, const int* in_sizes, int n_in,
                              void* d_out, int out_size, void* d_ws, size_t ws_size,
                              hipStream_t stream) {
    const float* imgR = (const float*)d_in[0];
    const float* imgI = (const float*)d_in[1];
    const float* trj  = (const float*)d_in[2];
    float* out = (float*)d_out;

    hipLaunchKernelGGL(nufft_mfma_kernel, dim3(512), dim3(512), 0, stream,
                       imgR, imgI, trj, out);
}